// Round 1
// baseline (210.498 us; speedup 1.0000x reference)
//
#include <hip/hip_runtime.h>

// RBF causal attention: out[m] = sum_{j<=m} exp(-0.125*||q_m - k_j||^2) * v_j
// B=2 H=16 S=2048 D=64, fp32 in/out.
// MFMA fp16 path: QK^T via hi/lo-split fp16 (3 MFMAs, ~fp32 accuracy);
// PV via fp16 with p scaled by 2^14 (avoids fp16 denormal band).

constexpr int S_LEN = 2048;
constexpr int HD    = 64;
constexpr int BM    = 128;   // Q rows per block (4 waves x 2 strips x 16)
constexpr int BN    = 64;    // K/V rows per tile
constexpr int NQT   = S_LEN / BM;   // 16
constexpr float SCALE = 0.125f;

typedef _Float16 half8 __attribute__((ext_vector_type(8)));
typedef _Float16 half4 __attribute__((ext_vector_type(4)));
typedef float    f32x4 __attribute__((ext_vector_type(4)));

// 16B-chunk XOR swizzle: row-major [rows][64 halves] stored as 8 chunks of 8
// halves per row; chunk c of row r lives at slot (c ^ (r&7)). Makes both the
// staging writes and the MFMA fragment reads hit the LDS bank floor.
__device__ __forceinline__ int swz(int row, int chunk) {
  return (row << 3) + (chunk ^ (row & 7));
}

__global__ __launch_bounds__(256, 2)
void rbf_causal_attn(const float* __restrict__ Qp, const float* __restrict__ Kp,
                     const float* __restrict__ Vp, float* __restrict__ Op) {
  __shared__ half8 sQh[BM * 8];      // 16 KB  q hi
  __shared__ half8 sQl[BM * 8];      // 16 KB  q lo
  __shared__ half8 sKh[BN * 8];      //  8 KB  k hi
  __shared__ half8 sKl[BN * 8];      //  8 KB  k lo
  __shared__ half8 sVtmp[BN * 8];    //  8 KB  v straight (transpose staging)
  __shared__ half8 sVt[HD * 8];      //  8 KB  v^T: row=d, col=j
  __shared__ half8 sP[4 * 16 * 8];   //  8 KB  per-wave P round-trip
  __shared__ float sQsq[BM];
  __shared__ float sKsq[BN];

  const int x    = blockIdx.x;
  // bh grouped by XCD (x&7) for K/V L2 locality; heavy q-tiles dispatched first.
  const int bh   = (x & 7) * 4 + ((x >> 3) >> 4);
  const int qt   = (NQT - 1) - ((x >> 3) & 15);
  const int t    = threadIdx.x;
  const int w    = t >> 6;       // wave 0..3
  const int lane = t & 63;
  const int ln   = lane & 15;
  const int q4   = lane >> 4;    // quad 0..3

  const float* Qg = Qp + ((size_t)bh * S_LEN + (size_t)qt * BM) * HD;
  const float* Kg = Kp + (size_t)bh * S_LEN * HD;
  const float* Vg = Vp + (size_t)bh * S_LEN * HD;

  // ---- stage Q tile (fp16 hi/lo, swizzled) + scaled row sum-of-squares ----
  #pragma unroll
  for (int i = 0; i < 8; ++i) {
    const int id  = t + 256 * i;      // float4 id, 0..2047 (coalesced)
    const int row = id >> 4;          // 0..127
    const int d4  = id & 15;
    const f32x4 f = *(const f32x4*)(Qg + row * HD + d4 * 4);
    half4 hv, lv;
    float ss = 0.f;
    #pragma unroll
    for (int c = 0; c < 4; ++c) {
      const float fv = f[c];
      const _Float16 h = (_Float16)fv;
      hv[c] = h;
      lv[c] = (_Float16)(fv - (float)h);
      ss += fv * fv;
    }
    ((half4*)&sQh[swz(row, d4 >> 1)])[d4 & 1] = hv;
    ((half4*)&sQl[swz(row, d4 >> 1)])[d4 & 1] = lv;
    #pragma unroll
    for (int m = 1; m < 16; m <<= 1) ss += __shfl_xor(ss, m);
    if ((t & 15) == 0) sQsq[row] = ss * SCALE;
  }

  f32x4 oacc[2][4] = {};   // [strip][d-tile], scaled by 2^14

  const int jt_max = 2 * qt + 1;
  for (int jt = 0; jt <= jt_max; ++jt) {
    __syncthreads();   // previous iteration's fragment reads complete
    // ---- stage K tile (hi/lo) + scaled row sum-of-squares ----
    #pragma unroll
    for (int i = 0; i < 4; ++i) {
      const int id  = t + 256 * i;    // 0..1023
      const int row = id >> 4;        // 0..63
      const int d4  = id & 15;
      const f32x4 f = *(const f32x4*)(Kg + ((size_t)jt * BN + row) * HD + d4 * 4);
      half4 hv, lv;
      float ss = 0.f;
      #pragma unroll
      for (int c = 0; c < 4; ++c) {
        const float fv = f[c];
        const _Float16 h = (_Float16)fv;
        hv[c] = h;
        lv[c] = (_Float16)(fv - (float)h);
        ss += fv * fv;
      }
      ((half4*)&sKh[swz(row, d4 >> 1)])[d4 & 1] = hv;
      ((half4*)&sKl[swz(row, d4 >> 1)])[d4 & 1] = lv;
      #pragma unroll
      for (int m = 1; m < 16; m <<= 1) ss += __shfl_xor(ss, m);
      if ((t & 15) == 0) sKsq[row] = ss * SCALE;
    }
    // ---- stage V tile straight (fp16) ----
    #pragma unroll
    for (int i = 0; i < 4; ++i) {
      const int id  = t + 256 * i;
      const int row = id >> 4;
      const int d4  = id & 15;
      const f32x4 f = *(const f32x4*)(Vg + ((size_t)jt * BN + row) * HD + d4 * 4);
      half4 hv;
      #pragma unroll
      for (int c = 0; c < 4; ++c) hv[c] = (_Float16)f[c];
      ((half4*)&sVtmp[swz(row, d4 >> 1)])[d4 & 1] = hv;
    }
    __syncthreads();   // staging visible
    // ---- transpose V into sVt (row = d, col = j) ----
    {
      const int d   = t & 63;
      const int jc0 = t >> 6;
      #pragma unroll
      for (int rep = 0; rep < 2; ++rep) {
        const int jc = jc0 + 4 * rep;   // j-chunk 0..7
        half8 v;
        #pragma unroll
        for (int jj = 0; jj < 8; ++jj)
          v[jj] = ((const _Float16*)&sVtmp[swz(jc * 8 + jj, d >> 3)])[d & 7];
        sVt[swz(d, jc)] = v;
      }
    }
    __syncthreads();   // sVt ready

    // ---- per-wave compute: Q rows [w*32, w*32+32) as two 16-row strips ----
    half8 qh[2][2], ql[2][2];   // [strip][k-chunk]
    #pragma unroll
    for (int s = 0; s < 2; ++s)
      #pragma unroll
      for (int kc = 0; kc < 2; ++kc) {
        const int row = w * 32 + s * 16 + ln;
        const int ch  = ((kc << 2) + q4) ^ (ln & 7);
        qh[s][kc] = sQh[(row << 3) + ch];
        ql[s][kc] = sQl[(row << 3) + ch];
      }

    // S = Q K^T for both strips; K fragments loaded once, used 6x.
    f32x4 acc[2][4] = {};
    #pragma unroll
    for (int kc = 0; kc < 2; ++kc)
      #pragma unroll
      for (int nt = 0; nt < 4; ++nt) {
        const int row = nt * 16 + ln;
        const int ch  = ((kc << 2) + q4) ^ (ln & 7);
        const half8 kh = sKh[(row << 3) + ch];
        const half8 kl = sKl[(row << 3) + ch];
        acc[0][nt] = __builtin_amdgcn_mfma_f32_16x16x32_f16(qh[0][kc], kh, acc[0][nt], 0, 0, 0);
        acc[0][nt] = __builtin_amdgcn_mfma_f32_16x16x32_f16(qh[0][kc], kl, acc[0][nt], 0, 0, 0);
        acc[0][nt] = __builtin_amdgcn_mfma_f32_16x16x32_f16(ql[0][kc], kh, acc[0][nt], 0, 0, 0);
        acc[1][nt] = __builtin_amdgcn_mfma_f32_16x16x32_f16(qh[1][kc], kh, acc[1][nt], 0, 0, 0);
        acc[1][nt] = __builtin_amdgcn_mfma_f32_16x16x32_f16(qh[1][kc], kl, acc[1][nt], 0, 0, 0);
        acc[1][nt] = __builtin_amdgcn_mfma_f32_16x16x32_f16(ql[1][kc], kh, acc[1][nt], 0, 0, 0);
      }

    // V fragments (B-operand: k = j, n = d), shared by both strips
    half8 vf[4][2];
    #pragma unroll
    for (int dt = 0; dt < 4; ++dt)
      #pragma unroll
      for (int kc = 0; kc < 2; ++kc) {
        const int row = dt * 16 + ln;
        vf[dt][kc] = sVt[(row << 3) + (((kc << 2) + q4) ^ (ln & 7))];
      }

    const bool need_mask = (jt >= 2 * qt);
    #pragma unroll
    for (int s = 0; s < 2; ++s) {
      const int m0 = w * 32 + s * 16;
      float qsqv[4];
      #pragma unroll
      for (int r = 0; r < 4; ++r) qsqv[r] = sQsq[m0 + q4 * 4 + r];
      #pragma unroll
      for (int nt = 0; nt < 4; ++nt) {
        const float ks = sKsq[nt * 16 + ln];
        #pragma unroll
        for (int r = 0; r < 4; ++r) {
          // p' = 2^14 * exp(2s*qk - s*q^2 - s*k^2)  (2^14 folded into exp arg)
          const float lg = 0.25f * acc[s][nt][r] - qsqv[r] - ks + 9.70406052597f;
          float p = __expf(lg);
          if (need_mask) {
            const int jg = jt * BN + nt * 16 + ln;
            const int mg = qt * BM + m0 + q4 * 4 + r;
            if (jg > mg) p = 0.f;
          }
          const int prow = q4 * 4 + r;       // C-layout: row = quad*4+reg
          const int col  = nt * 16 + ln;     //           col = lane&15
          ((_Float16*)&sP[(w << 7) + swz(prow, col >> 3)])[col & 7] = (_Float16)p;
        }
      }
      // Re-read P in A-operand layout (per-wave buffer, no barrier needed)
      half8 pa[2];
      #pragma unroll
      for (int kc = 0; kc < 2; ++kc)
        pa[kc] = sP[(w << 7) + swz(ln, (kc << 2) + q4)];
      #pragma unroll
      for (int dt = 0; dt < 4; ++dt)
        #pragma unroll
        for (int kc = 0; kc < 2; ++kc)
          oacc[s][dt] = __builtin_amdgcn_mfma_f32_16x16x32_f16(pa[kc], vf[dt][kc], oacc[s][dt], 0, 0, 0);
    }
  }

  // ---- epilogue: undo 2^14 scale, store fp32 ----
  #pragma unroll
  for (int s = 0; s < 2; ++s)
    #pragma unroll
    for (int dt = 0; dt < 4; ++dt)
      #pragma unroll
      for (int r = 0; r < 4; ++r) {
        const int row = qt * BM + w * 32 + s * 16 + q4 * 4 + r;
        Op[((size_t)bh * S_LEN + row) * HD + dt * 16 + ln] =
            oacc[s][dt][r] * 6.103515625e-05f;   // * 2^-14
      }
}

extern "C" void kernel_launch(void* const* d_in, const int* in_sizes, int n_in,
                              void* d_out, int out_size, void* d_ws, size_t ws_size,
                              hipStream_t stream) {
  const float* q = (const float*)d_in[0];
  const float* k = (const float*)d_in[1];
  const float* v = (const float*)d_in[2];
  float* o = (float*)d_out;
  rbf_causal_attn<<<dim3(32 * NQT), dim3(256), 0, stream>>>(q, k, v, o);
}

// Round 2
// 172.380 us; speedup vs baseline: 1.2211x; 1.2211x over previous
//
#include <hip/hip_runtime.h>

// RBF causal attention: out[m] = sum_{j<=m} exp(-0.125*||q_m - k_j||^2) * v_j
// B=2 H=16 S=2048 D=64, fp32 in/out.
// fp16 hi/lo-split QK (3 MFMAs ~ fp32 accuracy), fp16 PV with p scaled 2^14.
// R2: uniform work (qt-pair split, 17 j-tiles/block, atomicAdd on shared
// q-tiles), register-prefetch pipelining of K/V, direct transposed V staging,
// hoisted Q fragments, exp2f.

constexpr int S_LEN = 2048;
constexpr int HD    = 64;
constexpr int BM    = 128;   // Q rows per block tile (4 waves x 2 strips x 16)
constexpr int BN    = 64;    // K/V rows per tile
constexpr int NQT   = S_LEN / BM;   // 16
constexpr float SCALE = 0.125f;
constexpr float LOG2E = 1.44269504088896f;

typedef _Float16 half8 __attribute__((ext_vector_type(8)));
typedef _Float16 half4 __attribute__((ext_vector_type(4)));
typedef float    f32x4 __attribute__((ext_vector_type(4)));

// 16B-chunk XOR swizzle (rows of 64 halves = 8 chunks of 8).
__device__ __forceinline__ int swz(int row, int chunk) {
  return (row << 3) + (chunk ^ (row & 7));
}

__global__ __launch_bounds__(256, 2)
void rbf_causal_attn(const float* __restrict__ Qp, const float* __restrict__ Kp,
                     const float* __restrict__ Vp, float* __restrict__ Op) {
  __shared__ half8 sQh[BM * 8];      // 16 KB
  __shared__ half8 sQl[BM * 8];      // 16 KB
  __shared__ half8 sKh[BN * 8];      //  8 KB
  __shared__ half8 sKl[BN * 8];      //  8 KB
  __shared__ half8 sVt[HD * 8];      //  8 KB  v^T: row=d, col=j
  __shared__ half8 sP[4 * 16 * 8];   //  8 KB  per-wave P round-trip
  __shared__ float sQsq[BM];         // pre-scaled by SCALE*LOG2E
  __shared__ float sKsq[BN];

  const int x    = blockIdx.x;
  const int bh   = (x & 7) * 4 + ((x >> 3) & 3);  // 4 bh per XCD for K/V L2 reuse
  const int ph   = x >> 5;       // 0..15
  const int p    = ph & 7;       // pair index
  const int h    = ph >> 3;      // half 0/1
  const int qtA  = (NQT - 1) - p;        // 8..15
  const int nA   = 2 * qtA + 2;          // 18..32 iters for tile A
  const int qtB  = p;                    // 0..7 (entirely inside half 1)

  const int t    = threadIdx.x;
  const int w    = t >> 6;
  const int lane = t & 63;
  const int ln   = lane & 15;
  const int q4   = lane >> 4;

  const float* Kg = Kp + (size_t)bh * S_LEN * HD;
  const float* Vg = Vp + (size_t)bh * S_LEN * HD;

  f32x4 kreg[4];      // K prefetch registers (one tile)
  float vreg[16];     // V prefetch registers (one tile, column d=lane)
  half8 qh[2][2], ql[2][2];
  f32x4 oacc[2][4] = {};   // scaled by 2^14

  // ---- stage Q tile: fp16 hi/lo into LDS + scaled row |q|^2 ----
  auto stage_q = [&](int qt) {
    const float* Qg = Qp + ((size_t)bh * S_LEN + (size_t)qt * BM) * HD;
    #pragma unroll
    for (int i = 0; i < 8; ++i) {
      const int id  = t + 256 * i;
      const int row = id >> 4;
      const int d4  = id & 15;
      const f32x4 f = *(const f32x4*)(Qg + row * HD + d4 * 4);
      half4 hv, lv;
      float ss = 0.f;
      #pragma unroll
      for (int c = 0; c < 4; ++c) {
        const float fv = f[c];
        const _Float16 hi = (_Float16)fv;
        hv[c] = hi;
        lv[c] = (_Float16)(fv - (float)hi);
        ss += fv * fv;
      }
      ((half4*)&sQh[swz(row, d4 >> 1)])[d4 & 1] = hv;
      ((half4*)&sQl[swz(row, d4 >> 1)])[d4 & 1] = lv;
      #pragma unroll
      for (int m = 1; m < 16; m <<= 1) ss += __shfl_xor(ss, m);
      if ((t & 15) == 0) sQsq[row] = ss * (SCALE * LOG2E);
    }
  };

  // ---- hoist this wave's Q fragments into registers (call after barrier) ----
  auto load_q_frags = [&]() {
    #pragma unroll
    for (int s = 0; s < 2; ++s)
      #pragma unroll
      for (int kc = 0; kc < 2; ++kc) {
        const int row = w * 32 + s * 16 + ln;
        const int ch  = ((kc << 2) + q4) ^ (ln & 7);
        qh[s][kc] = sQh[(row << 3) + ch];
        ql[s][kc] = sQl[(row << 3) + ch];
      }
  };

  // ---- issue global loads for j-tile jt into registers (no wait) ----
  auto prefetch = [&](int jt) {
    const float* Kt = Kg + (size_t)jt * BN * HD;
    #pragma unroll
    for (int i = 0; i < 4; ++i) {
      const int id  = t + 256 * i;
      kreg[i] = *(const f32x4*)(Kt + (id >> 4) * HD + (id & 15) * 4);
    }
    const float* Vt = Vg + (size_t)jt * BN * HD;
    #pragma unroll
    for (int i = 0; i < 16; ++i)
      vreg[i] = Vt[(w * 16 + i) * HD + lane];   // 256B-coalesced per instr
  };

  // ---- convert prefetched K/V registers into LDS ----
  auto stage_kv = [&]() {
    #pragma unroll
    for (int i = 0; i < 4; ++i) {
      const int id  = t + 256 * i;
      const int row = id >> 4;
      const int d4  = id & 15;
      const f32x4 f = kreg[i];
      half4 hv, lv;
      float ss = 0.f;
      #pragma unroll
      for (int c = 0; c < 4; ++c) {
        const float fv = f[c];
        const _Float16 hi = (_Float16)fv;
        hv[c] = hi;
        lv[c] = (_Float16)(fv - (float)hi);
        ss += fv * fv;
      }
      ((half4*)&sKh[swz(row, d4 >> 1)])[d4 & 1] = hv;
      ((half4*)&sKl[swz(row, d4 >> 1)])[d4 & 1] = lv;
      #pragma unroll
      for (int m = 1; m < 16; m <<= 1) ss += __shfl_xor(ss, m);
      if ((t & 15) == 0) sKsq[row] = ss * (SCALE * LOG2E);
    }
    // V: thread holds column d=lane, rows j = w*16 .. w*16+15 -> transposed store
    half8 v0, v1;
    #pragma unroll
    for (int i = 0; i < 8; ++i) { v0[i] = (_Float16)vreg[i]; v1[i] = (_Float16)vreg[8 + i]; }
    sVt[swz(lane, 2 * w + 0)] = v0;
    sVt[swz(lane, 2 * w + 1)] = v1;
  };

  // ---- one j-tile of compute: QK (hi/lo), exp2, P round-trip, PV ----
  auto compute = [&](int qt, int jt) {
    f32x4 acc[2][4] = {};
    #pragma unroll
    for (int kc = 0; kc < 2; ++kc)
      #pragma unroll
      for (int nt = 0; nt < 4; ++nt) {
        const int row = nt * 16 + ln;
        const int ch  = ((kc << 2) + q4) ^ (ln & 7);
        const half8 kh = sKh[(row << 3) + ch];
        const half8 kl = sKl[(row << 3) + ch];
        acc[0][nt] = __builtin_amdgcn_mfma_f32_16x16x32_f16(qh[0][kc], kh, acc[0][nt], 0, 0, 0);
        acc[0][nt] = __builtin_amdgcn_mfma_f32_16x16x32_f16(qh[0][kc], kl, acc[0][nt], 0, 0, 0);
        acc[0][nt] = __builtin_amdgcn_mfma_f32_16x16x32_f16(ql[0][kc], kh, acc[0][nt], 0, 0, 0);
        acc[1][nt] = __builtin_amdgcn_mfma_f32_16x16x32_f16(qh[1][kc], kh, acc[1][nt], 0, 0, 0);
        acc[1][nt] = __builtin_amdgcn_mfma_f32_16x16x32_f16(qh[1][kc], kl, acc[1][nt], 0, 0, 0);
        acc[1][nt] = __builtin_amdgcn_mfma_f32_16x16x32_f16(ql[1][kc], kh, acc[1][nt], 0, 0, 0);
      }

    half8 vf[4][2];
    #pragma unroll
    for (int dt = 0; dt < 4; ++dt)
      #pragma unroll
      for (int kc = 0; kc < 2; ++kc) {
        const int row = dt * 16 + ln;
        vf[dt][kc] = sVt[(row << 3) + (((kc << 2) + q4) ^ (ln & 7))];
      }

    const bool need_mask = (jt >= 2 * qt);
    #pragma unroll
    for (int s = 0; s < 2; ++s) {
      const int m0 = w * 32 + s * 16;
      float qsqv[4];
      #pragma unroll
      for (int r = 0; r < 4; ++r) qsqv[r] = sQsq[m0 + q4 * 4 + r];
      #pragma unroll
      for (int nt = 0; nt < 4; ++nt) {
        const float ks = sKsq[nt * 16 + ln];
        #pragma unroll
        for (int r = 0; r < 4; ++r) {
          // log2(p') = 2s*log2e*qk - s*log2e*q^2 - s*log2e*k^2 + 14
          const float lg = (2.f * SCALE * LOG2E) * acc[s][nt][r] - qsqv[r] - ks + 14.0f;
          float pv = exp2f(lg);
          if (need_mask) {
            const int jg = jt * BN + nt * 16 + ln;
            const int mg = qt * BM + m0 + q4 * 4 + r;
            if (jg > mg) pv = 0.f;
          }
          const int prow = q4 * 4 + r;
          const int col  = nt * 16 + ln;
          ((_Float16*)&sP[(w << 7) + swz(prow, col >> 3)])[col & 7] = (_Float16)pv;
        }
      }
      half8 pa[2];
      #pragma unroll
      for (int kc = 0; kc < 2; ++kc)
        pa[kc] = sP[(w << 7) + swz(ln, (kc << 2) + q4)];
      #pragma unroll
      for (int dt = 0; dt < 4; ++dt)
        #pragma unroll
        for (int kc = 0; kc < 2; ++kc)
          oacc[s][dt] = __builtin_amdgcn_mfma_f32_16x16x32_f16(pa[kc], vf[dt][kc], oacc[s][dt], 0, 0, 0);
    }
  };

  // ---- flush accumulator (×2^-14); atomic for shared tiles ----
  auto flush = [&](int qt, bool atomic) {
    #pragma unroll
    for (int s = 0; s < 2; ++s)
      #pragma unroll
      for (int dt = 0; dt < 4; ++dt)
        #pragma unroll
        for (int r = 0; r < 4; ++r) {
          const int row = qt * BM + w * 32 + s * 16 + q4 * 4 + r;
          float* addr = Op + ((size_t)bh * S_LEN + row) * HD + dt * 16 + ln;
          const float val = oacc[s][dt][r] * 6.103515625e-05f;
          if (atomic) atomicAdd(addr, val); else *addr = val;
        }
  };

  // ---- main: 17 uniform j-tile iterations ----
  int qt = qtA;
  int jt = h * 17;            // h=1 starts at jt=17 < nA (nA >= 18)
  stage_q(qtA);
  prefetch(jt);
  __syncthreads();
  load_q_frags();

  #pragma unroll 1
  for (int step = 0; step < 17; ++step) {
    bool crossed = false;
    if (qt == qtA && jt == nA) {       // half 1 crosses into tile B
      flush(qtA, true);
      #pragma unroll
      for (int s = 0; s < 2; ++s)
        #pragma unroll
        for (int dt = 0; dt < 4; ++dt) oacc[s][dt] = f32x4{0.f, 0.f, 0.f, 0.f};
      stage_q(qtB);
      qt = qtB; jt = 0;
      crossed = true;
    }
    stage_kv();
    if (step + 1 < 17) {               // prefetch next tile (overlaps compute)
      int njt = jt + 1;
      if (qt == qtA && njt == nA) njt = 0;
      prefetch(njt);
    }
    __syncthreads();
    if (crossed) load_q_frags();
    compute(qt, jt);
    __syncthreads();
    ++jt;
  }
  flush(qt, qt == qtA);
}

extern "C" void kernel_launch(void* const* d_in, const int* in_sizes, int n_in,
                              void* d_out, int out_size, void* d_ws, size_t ws_size,
                              hipStream_t stream) {
  const float* q = (const float*)d_in[0];
  const float* k = (const float*)d_in[1];
  const float* v = (const float*)d_in[2];
  float* o = (float*)d_out;
  hipMemsetAsync(d_out, 0, (size_t)out_size * sizeof(float), stream);
  rbf_causal_attn<<<dim3(512), dim3(256), 0, stream>>>(q, k, v, o);
}